// Round 12
// baseline (115.584 us; speedup 1.0000x reference)
//
#include <hip/hip_runtime.h>
#include <math.h>

#define HIDDEN 64
#define RPB 32          // rays per block
#define CAP 4096        // max samples buffered per chunk (32 KB LDS of float2)

typedef _Float16 half8   __attribute__((ext_vector_type(8)));
typedef _Float16 half2_t __attribute__((ext_vector_type(2)));
typedef float    f32x16  __attribute__((ext_vector_type(16)));
typedef int      int4_t  __attribute__((ext_vector_type(4)));

// DPP add: v + dpp_perm(v), old=0, bound_ctrl=1.
template <int CTRL, int RMASK>
__device__ __forceinline__ float dpp_add(float v) {
    int t = __builtin_amdgcn_update_dpp(0, __builtin_bit_cast(int, v),
                                        CTRL, RMASK, 0xF, true);
    return v + __builtin_bit_cast(float, t);
}

__device__ __forceinline__ float bcast_lane(float v, int lane) {
    return __builtin_bit_cast(float,
        __builtin_amdgcn_readlane(__builtin_bit_cast(int, v), lane));
}

__device__ __forceinline__ half2_t pack2(float a, float b) {
    return __builtin_bit_cast(half2_t, __builtin_amdgcn_cvt_pkrtz(a, b));
}

__device__ __forceinline__ half2_t pk_relu(half2_t h) {
    half2_t r;
    asm("v_pk_max_f16 %0, %1, 0" : "=v"(r) : "v"(h));
    return r;
}

// full wave64 inclusive scan (6 DPP adds)
__device__ __forceinline__ float scan64(float v) {
    v = dpp_add<0x111, 0xF>(v);
    v = dpp_add<0x112, 0xF>(v);
    v = dpp_add<0x114, 0xF>(v);
    v = dpp_add<0x118, 0xF>(v);
    v = dpp_add<0x142, 0xA>(v);   // row_bcast:15 -> rows 1,3
    v = dpp_add<0x143, 0xC>(v);   // row_bcast:31 -> rows 2,3
    return v;
}

// layer1 (MFMA) + layer2 (pack/pk_relu/dot2) + cross-half combine -> z
__device__ __forceinline__ float mlp_z(half8 a0, half8 a1,
                                       const half2_t* w2a, const half2_t* w2b,
                                       half8 bf, int xaddr, float bias2) {
    const f32x16 zc = {};
    const f32x16 d0 = __builtin_amdgcn_mfma_f32_32x32x16_f16(a0, bf, zc, 0, 0, 0);
    const f32x16 d1 = __builtin_amdgcn_mfma_f32_32x32x16_f16(a1, bf, zc, 0, 0, 0);
    float c0 = 0.0f, c1 = 0.0f, c2 = 0.0f, c3 = 0.0f;
    #pragma unroll
    for (int r8 = 0; r8 < 8; r8 += 4) {
        c0 = __builtin_amdgcn_fdot2(pk_relu(pack2(d0[2*r8+0], d0[2*r8+1])), w2a[r8+0], c0, false);
        c1 = __builtin_amdgcn_fdot2(pk_relu(pack2(d0[2*r8+2], d0[2*r8+3])), w2a[r8+1], c1, false);
        c2 = __builtin_amdgcn_fdot2(pk_relu(pack2(d0[2*r8+4], d0[2*r8+5])), w2a[r8+2], c2, false);
        c3 = __builtin_amdgcn_fdot2(pk_relu(pack2(d0[2*r8+6], d0[2*r8+7])), w2a[r8+3], c3, false);
    }
    #pragma unroll
    for (int r8 = 0; r8 < 8; r8 += 4) {
        c0 = __builtin_amdgcn_fdot2(pk_relu(pack2(d1[2*r8+0], d1[2*r8+1])), w2b[r8+0], c0, false);
        c1 = __builtin_amdgcn_fdot2(pk_relu(pack2(d1[2*r8+2], d1[2*r8+3])), w2b[r8+1], c1, false);
        c2 = __builtin_amdgcn_fdot2(pk_relu(pack2(d1[2*r8+4], d1[2*r8+5])), w2b[r8+2], c2, false);
        c3 = __builtin_amdgcn_fdot2(pk_relu(pack2(d1[2*r8+6], d1[2*r8+7])), w2b[r8+3], c3, false);
    }
    const float acc = (c0 + c1) + (c2 + c3);
    const int oth = __builtin_amdgcn_ds_bpermute(xaddr, __builtin_bit_cast(int, acc));
    return acc + __builtin_bit_cast(float, oth) + bias2;
}

// Single fused kernel. Block b owns rays [RPB*b, RPB*b+RPB).
//  - binary-search segment bounds (33 lanes, once per block)
//  - phase A: dense MFMA MLP over the block's sample range -> {sval,tm} in LDS
//  - phase B: each wave scans 8 rays from LDS (DPP scan, register carries)
__global__ __launch_bounds__(256, 4) void nerf_fused_kernel(
    const float* __restrict__ rays_o, const float* __restrict__ rays_d,
    const float* __restrict__ W1, const float* __restrict__ b1,
    const float* __restrict__ W2, const float* __restrict__ b2,
    const float* __restrict__ t_starts, const int* __restrict__ ray_indices,
    float* __restrict__ out, int n_rays, int n_samples)
{
    __shared__ float2 smp[CAP];     // {sval, tm} per sample in chunk
    __shared__ int    sBounds[RPB + 1];

    const int tid  = threadIdx.x;
    const int lane = tid & 63;
    const int w    = tid >> 6;      // wave index in block (0..3)
    const int n    = lane & 31;
    const int q    = lane >> 5;
    const int ray0 = blockIdx.x * RPB;

    // ---- per-block segment bounds: lower_bound(ray_indices, ray0 + t) ----
    if (tid <= RPB) {
        const int target = ray0 + tid;
        int lo = 0, hi = n_samples;
        while (lo < hi) {
            const int mid = (lo + hi) >> 1;
            if (ray_indices[mid] < target) lo = mid + 1; else hi = mid;
        }
        sBounds[tid] = lo;
    }

    // ---- MLP weight fragments (R10-proven in-register build) ----
    half8 a0 = {}, a1 = {};
    if (q == 0) {
        const int m = n;
        a0[0] = (_Float16)W1[0 * HIDDEN + m];
        a0[1] = (_Float16)W1[1 * HIDDEN + m];
        a0[2] = (_Float16)W1[2 * HIDDEN + m];
        a0[3] = (_Float16)b1[m];
        a1[0] = (_Float16)W1[0 * HIDDEN + 32 + m];
        a1[1] = (_Float16)W1[1 * HIDDEN + 32 + m];
        a1[2] = (_Float16)W1[2 * HIDDEN + 32 + m];
        a1[3] = (_Float16)b1[32 + m];
    }
    half2_t w2a[8], w2b[8];
    #pragma unroll
    for (int r8 = 0; r8 < 8; ++r8) {
        const int row = 2 * (r8 & 1) + 8 * (r8 >> 1) + 4 * q;
        half2_t pa, pb;
        pa[0] = (_Float16)W2[row];      pa[1] = (_Float16)W2[row + 1];
        pb[0] = (_Float16)W2[row + 32]; pb[1] = (_Float16)W2[row + 33];
        w2a[r8] = pa; w2b[r8] = pb;
    }
    const float bias2 = b2[0];
    const int xaddr = (lane ^ 32) << 2;
    const int bmask = (q == 0) ? ~0 : 0;

    __syncthreads();
    const int S0 = sBounds[0];
    const int S1 = sBounds[RPB];

    // per-ray accumulators for this wave's 8 rays (persist across chunks)
    float carry[8], op[8], dp[8];
    #pragma unroll
    for (int k = 0; k < 8; ++k) { carry[k] = 0.0f; op[k] = 0.0f; dp[k] = 0.0f; }

    for (int cs = S0; cs < S1; cs += CAP) {
        const int ce = (cs + CAP < S1) ? (cs + CAP) : S1;

        // ---- phase A: densities for samples [cs, ce) -> LDS ----
        for (int base = cs + w * 64; base < ce; base += 256) {
            const int ia = base + n;
            const int ib = ia + 32;
            const bool va = (ia < ce);
            const bool vb = (ib < ce);
            const int ca = va ? ia : (ce - 1);
            const int cb = vb ? ib : (ce - 1);

            const float tm_a = t_starts[ca] + 0.0025f;   // te = ts + 0.005
            const float tm_b = t_starts[cb] + 0.0025f;
            const int   ria  = ray_indices[ca];
            const int   rib  = ray_indices[cb];

            const float pxa = fmaf(rays_d[3 * ria + 0], tm_a, rays_o[3 * ria + 0]);
            const float pya = fmaf(rays_d[3 * ria + 1], tm_a, rays_o[3 * ria + 1]);
            const float pza = fmaf(rays_d[3 * ria + 2], tm_a, rays_o[3 * ria + 2]);
            const float pxb = fmaf(rays_d[3 * rib + 0], tm_b, rays_o[3 * rib + 0]);
            const float pyb = fmaf(rays_d[3 * rib + 1], tm_b, rays_o[3 * rib + 1]);
            const float pzb = fmaf(rays_d[3 * rib + 2], tm_b, rays_o[3 * rib + 2]);

            const int a01 = __builtin_bit_cast(int, __builtin_amdgcn_cvt_pkrtz(pxa, pya)) & bmask;
            const int a23 = __builtin_bit_cast(int, __builtin_amdgcn_cvt_pkrtz(pza, 1.0f)) & bmask;
            const int b01 = __builtin_bit_cast(int, __builtin_amdgcn_cvt_pkrtz(pxb, pyb)) & bmask;
            const int b23 = __builtin_bit_cast(int, __builtin_amdgcn_cvt_pkrtz(pzb, 1.0f)) & bmask;
            const int4_t bia = {a01, a23, 0, 0};
            const int4_t bib = {b01, b23, 0, 0};

            const float z_a = mlp_z(a0, a1, w2a, w2b, __builtin_bit_cast(half8, bia), xaddr, bias2);
            const float z_b = mlp_z(a0, a1, w2a, w2b, __builtin_bit_cast(half8, bib), xaddr, bias2);

            const float sg_a = fmaxf(z_a, 0.0f) + __logf(1.0f + __expf(-fabsf(z_a)));
            const float sg_b = fmaxf(z_b, 0.0f) + __logf(1.0f + __expf(-fabsf(z_b)));

            if (q == 0) {
                if (va) smp[ia - cs] = make_float2(sg_a * 0.005f, tm_a);
                if (vb) smp[ib - cs] = make_float2(sg_b * 0.005f, tm_b);
            }
        }
        __syncthreads();

        // ---- phase B: this wave scans its 8 rays' intersection with chunk ----
        #pragma unroll
        for (int k = 0; k < 8; ++k) {
            const int r = w * 8 + k;
            const int seg_start = sBounds[r];
            const int seg_end   = sBounds[r + 1];
            const int lo = (seg_start > cs) ? seg_start : cs;
            const int hi = (seg_end   < ce) ? seg_end   : ce;

            float c = carry[k], o = op[k], d = dp[k];
            for (int base = lo; base < hi; base += 64) {
                const int  i     = base + lane;
                const bool valid = (i < hi);
                const int  idx   = (valid ? i : (hi - 1)) - cs;

                const float2 v  = smp[idx];
                const float  sv = valid ? v.x : 0.0f;

                const float scn  = scan64(sv);
                const float incl = c + scn;
                const float wt   = __expf(sv - incl) - __expf(-incl); // 0 if sv==0

                o += wt;
                d  = fmaf(wt, v.y, d);
                c += bcast_lane(scn, 63);
            }
            carry[k] = c; op[k] = o; dp[k] = d;
        }
        __syncthreads();   // smp reuse safety for next chunk
    }

    // ---- outputs: wave w writes rays w*8 .. w*8+7 ----
    #pragma unroll
    for (int k = 0; k < 8; ++k) {
        const int r = ray0 + w * 8 + k;
        if (r >= n_rays) continue;
        const float op_tot = bcast_lane(scan64(op[k]), 63);
        const float dp_tot = bcast_lane(scan64(dp[k]), 63);
        if (lane == 0) {
            const int seg_start = sBounds[w * 8 + k];
            const int seg_end   = sBounds[w * 8 + k + 1];
            if (seg_start >= seg_end) {
                out[2 * r + 0] = 0.0f;
                out[2 * r + 1] = 0.0f;
            } else {
                const float tiny = 1.17549435e-38f;
                out[2 * r + 0] = op_tot;
                out[2 * r + 1] = dp_tot / fmaxf(op_tot, tiny);
            }
        }
    }
}

extern "C" void kernel_launch(void* const* d_in, const int* in_sizes, int n_in,
                              void* d_out, int out_size, void* d_ws, size_t ws_size,
                              hipStream_t stream) {
    const float* rays_o      = (const float*)d_in[0];
    const float* rays_d      = (const float*)d_in[1];
    const float* W1          = (const float*)d_in[2];
    const float* b1          = (const float*)d_in[3];
    const float* W2          = (const float*)d_in[4];
    const float* b2          = (const float*)d_in[5];
    const float* t_starts    = (const float*)d_in[6];
    const int*   ray_indices = (const int*)d_in[8];

    const int n_rays    = in_sizes[0] / 3;
    const int n_samples = in_sizes[6];

    float* out = (float*)d_out;

    const int blocks = (n_rays + RPB - 1) / RPB;   // 1024 blocks of 256
    nerf_fused_kernel<<<blocks, 256, 0, stream>>>(
        rays_o, rays_d, W1, b1, W2, b2, t_starts, ray_indices,
        out, n_rays, n_samples);
}

// Round 13
// 114.737 us; speedup vs baseline: 1.0074x; 1.0074x over previous
//
#include <hip/hip_runtime.h>
#include <math.h>

#define HIDDEN 64
#define WAVE_SAMPLES 512          // samples per wave in the dense MLP kernel
#define SVAL_OFFSET 262144        // byte offset of {sval,tm} float2[] in d_ws

typedef _Float16 half8   __attribute__((ext_vector_type(8)));
typedef _Float16 half2_t __attribute__((ext_vector_type(2)));
typedef float    f32x16  __attribute__((ext_vector_type(16)));
typedef int      int4_t  __attribute__((ext_vector_type(4)));

// DPP add: v + dpp_perm(v), old=0, bound_ctrl=1.
template <int CTRL, int RMASK>
__device__ __forceinline__ float dpp_add(float v) {
    int t = __builtin_amdgcn_update_dpp(0, __builtin_bit_cast(int, v),
                                        CTRL, RMASK, 0xF, true);
    return v + __builtin_bit_cast(float, t);
}

__device__ __forceinline__ float bcast_lane(float v, int lane) {
    return __builtin_bit_cast(float,
        __builtin_amdgcn_readlane(__builtin_bit_cast(int, v), lane));
}

__device__ __forceinline__ half2_t pack2(float a, float b) {
    return __builtin_bit_cast(half2_t, __builtin_amdgcn_cvt_pkrtz(a, b));
}

__device__ __forceinline__ half2_t pk_relu(half2_t h) {
    half2_t r;
    asm("v_pk_max_f16 %0, %1, 0" : "=v"(r) : "v"(h));
    return r;
}

// full wave64 inclusive scan (6 DPP adds)
__device__ __forceinline__ float scan64(float v) {
    v = dpp_add<0x111, 0xF>(v);
    v = dpp_add<0x112, 0xF>(v);
    v = dpp_add<0x114, 0xF>(v);
    v = dpp_add<0x118, 0xF>(v);
    v = dpp_add<0x142, 0xA>(v);   // row_bcast:15 -> rows 1,3
    v = dpp_add<0x143, 0xC>(v);   // row_bcast:31 -> rows 2,3
    return v;
}

// layer1 (MFMA) + layer2 (pack/pk_relu/dot2) + cross-half combine -> z
__device__ __forceinline__ float mlp_z(half8 a0, half8 a1,
                                       const half2_t* w2a, const half2_t* w2b,
                                       half8 bf, int xaddr, float bias2) {
    const f32x16 zc = {};
    const f32x16 d0 = __builtin_amdgcn_mfma_f32_32x32x16_f16(a0, bf, zc, 0, 0, 0);
    const f32x16 d1 = __builtin_amdgcn_mfma_f32_32x32x16_f16(a1, bf, zc, 0, 0, 0);
    float c0 = 0.0f, c1 = 0.0f, c2 = 0.0f, c3 = 0.0f;
    #pragma unroll
    for (int r8 = 0; r8 < 8; r8 += 4) {
        c0 = __builtin_amdgcn_fdot2(pk_relu(pack2(d0[2*r8+0], d0[2*r8+1])), w2a[r8+0], c0, false);
        c1 = __builtin_amdgcn_fdot2(pk_relu(pack2(d0[2*r8+2], d0[2*r8+3])), w2a[r8+1], c1, false);
        c2 = __builtin_amdgcn_fdot2(pk_relu(pack2(d0[2*r8+4], d0[2*r8+5])), w2a[r8+2], c2, false);
        c3 = __builtin_amdgcn_fdot2(pk_relu(pack2(d0[2*r8+6], d0[2*r8+7])), w2a[r8+3], c3, false);
    }
    #pragma unroll
    for (int r8 = 0; r8 < 8; r8 += 4) {
        c0 = __builtin_amdgcn_fdot2(pk_relu(pack2(d1[2*r8+0], d1[2*r8+1])), w2b[r8+0], c0, false);
        c1 = __builtin_amdgcn_fdot2(pk_relu(pack2(d1[2*r8+2], d1[2*r8+3])), w2b[r8+1], c1, false);
        c2 = __builtin_amdgcn_fdot2(pk_relu(pack2(d1[2*r8+4], d1[2*r8+5])), w2b[r8+2], c2, false);
        c3 = __builtin_amdgcn_fdot2(pk_relu(pack2(d1[2*r8+6], d1[2*r8+7])), w2b[r8+3], c3, false);
    }
    const float acc = (c0 + c1) + (c2 + c3);
    const int oth = __builtin_amdgcn_ds_bpermute(xaddr, __builtin_bit_cast(int, acc));
    return acc + __builtin_bit_cast(float, oth) + bias2;
}

// Kernel 1 (dense, sample-parallel): sval/tm for every sample -> ws (float2),
// fused first_idx scatter. No serial dependencies between iterations.
__global__ __launch_bounds__(256, 6) void mlp_density_kernel(
    const float* __restrict__ rays_o, const float* __restrict__ rays_d,
    const float* __restrict__ W1, const float* __restrict__ b1,
    const float* __restrict__ W2, const float* __restrict__ b2,
    const float* __restrict__ t_starts, const int* __restrict__ ray_indices,
    float2* __restrict__ smp_out, int* __restrict__ first_idx,
    int n_samples, int n_rays)
{
    const int tid  = threadIdx.x;
    const int lane = tid & 63;
    const int wave = (blockIdx.x * blockDim.x + tid) >> 6;
    const int n = lane & 31;
    const int q = lane >> 5;

    const int base0 = wave * WAVE_SAMPLES;
    if (base0 >= n_samples) return;
    const int lim = (base0 + WAVE_SAMPLES < n_samples) ? (base0 + WAVE_SAMPLES) : n_samples;

    // ---- preamble: A fragments + W2 f16 pairs (in-register, proven) ----
    half8 a0 = {}, a1 = {};
    if (q == 0) {
        const int m = n;
        a0[0] = (_Float16)W1[0 * HIDDEN + m];
        a0[1] = (_Float16)W1[1 * HIDDEN + m];
        a0[2] = (_Float16)W1[2 * HIDDEN + m];
        a0[3] = (_Float16)b1[m];
        a1[0] = (_Float16)W1[0 * HIDDEN + 32 + m];
        a1[1] = (_Float16)W1[1 * HIDDEN + 32 + m];
        a1[2] = (_Float16)W1[2 * HIDDEN + 32 + m];
        a1[3] = (_Float16)b1[32 + m];
    }
    half2_t w2a[8], w2b[8];
    #pragma unroll
    for (int r8 = 0; r8 < 8; ++r8) {
        const int row = 2 * (r8 & 1) + 8 * (r8 >> 1) + 4 * q;
        half2_t pa, pb;
        pa[0] = (_Float16)W2[row];      pa[1] = (_Float16)W2[row + 1];
        pb[0] = (_Float16)W2[row + 32]; pb[1] = (_Float16)W2[row + 33];
        w2a[r8] = pa; w2b[r8] = pb;
    }
    const float bias2 = b2[0];
    const int xaddr = (lane ^ 32) << 2;
    const int bmask = (q == 0) ? ~0 : 0;

    for (int base = base0; base < lim; base += 64) {
        // ---- fused first_idx scatter: lane l covers sample base+l ----
        const int iS = base + lane;
        if (iS < n_samples) {
            const int cur  = ray_indices[iS];
            const int prev = (iS == 0) ? -1 : ray_indices[iS - 1];
            for (int r = prev + 1; r <= cur; ++r) first_idx[r] = iS;
            if (iS == n_samples - 1) {
                for (int r = cur + 1; r < n_rays; ++r) first_idx[r] = n_samples;
            }
        }

        // ---- density for samples base+n (half A) and base+32+n (half B) ----
        const int ia = base + n;
        const int ib = ia + 32;
        const bool va = (ia < n_samples);
        const bool vb = (ib < n_samples);
        const int ca = va ? ia : (n_samples - 1);
        const int cb = vb ? ib : (n_samples - 1);

        const float tm_a = t_starts[ca] + 0.0025f;   // te = ts + 0.005
        const float tm_b = t_starts[cb] + 0.0025f;
        const int   ria  = ray_indices[ca];
        const int   rib  = ray_indices[cb];

        const float pxa = fmaf(rays_d[3 * ria + 0], tm_a, rays_o[3 * ria + 0]);
        const float pya = fmaf(rays_d[3 * ria + 1], tm_a, rays_o[3 * ria + 1]);
        const float pza = fmaf(rays_d[3 * ria + 2], tm_a, rays_o[3 * ria + 2]);
        const float pxb = fmaf(rays_d[3 * rib + 0], tm_b, rays_o[3 * rib + 0]);
        const float pyb = fmaf(rays_d[3 * rib + 1], tm_b, rays_o[3 * rib + 1]);
        const float pzb = fmaf(rays_d[3 * rib + 2], tm_b, rays_o[3 * rib + 2]);

        const int a01 = __builtin_bit_cast(int, __builtin_amdgcn_cvt_pkrtz(pxa, pya)) & bmask;
        const int a23 = __builtin_bit_cast(int, __builtin_amdgcn_cvt_pkrtz(pza, 1.0f)) & bmask;
        const int b01 = __builtin_bit_cast(int, __builtin_amdgcn_cvt_pkrtz(pxb, pyb)) & bmask;
        const int b23 = __builtin_bit_cast(int, __builtin_amdgcn_cvt_pkrtz(pzb, 1.0f)) & bmask;
        const int4_t bia = {a01, a23, 0, 0};
        const int4_t bib = {b01, b23, 0, 0};

        const float z_a = mlp_z(a0, a1, w2a, w2b, __builtin_bit_cast(half8, bia), xaddr, bias2);
        const float z_b = mlp_z(a0, a1, w2a, w2b, __builtin_bit_cast(half8, bib), xaddr, bias2);

        const float sg_a = fmaxf(z_a, 0.0f) + __logf(1.0f + __expf(-fabsf(z_a)));
        const float sg_b = fmaxf(z_b, 0.0f) + __logf(1.0f + __expf(-fabsf(z_b)));

        if (q == 0) {
            if (va) smp_out[ia] = make_float2(sg_a * 0.005f, tm_a);
            if (vb) smp_out[ib] = make_float2(sg_b * 0.005f, tm_b);
        }
    }
}

// Kernel 2 (light): one wave64 per ray, lane = sample. One coalesced float2
// load per sample; wave64 DPP scan -> weights -> opacity/depth.
__global__ __launch_bounds__(256, 8) void render_scan_kernel(
    const float2* __restrict__ smp, const int* __restrict__ first_idx,
    float* __restrict__ out, int n_rays, int n_samples)
{
    const int tid  = threadIdx.x;
    const int lane = tid & 63;
    const int ray  = (blockIdx.x * blockDim.x + tid) >> 6;
    if (ray >= n_rays) return;

    // issue both bound loads immediately (independent)
    const int seg_start = first_idx[ray];
    const int seg_end   = (ray + 1 < n_rays) ? first_idx[ray + 1] : n_samples;
    if (seg_start >= seg_end) {
        if (lane == 0) { out[2 * ray] = 0.0f; out[2 * ray + 1] = 0.0f; }
        return;
    }

    float carry = 0.0f, op_acc = 0.0f, depth_acc = 0.0f;
    const int last = seg_end - 1;

    for (int base = seg_start; base < seg_end; base += 64) {
        const int  i     = base + lane;
        const bool valid = (i < seg_end);
        const int  ic    = valid ? i : last;

        const float2 v  = smp[ic];
        const float  sv = valid ? v.x : 0.0f;

        const float scan = scan64(sv);
        const float incl = carry + scan;
        const float w    = __expf(sv - incl) - __expf(-incl);   // 0 when sv==0

        op_acc    += w;
        depth_acc  = fmaf(w, v.y, depth_acc);
        carry     += bcast_lane(scan, 63);
    }

    const float op_tot = bcast_lane(scan64(op_acc), 63);
    const float dp_tot = bcast_lane(scan64(depth_acc), 63);

    if (lane == 0) {
        const float tiny = 1.17549435e-38f;
        out[2 * ray + 0] = op_tot;
        out[2 * ray + 1] = dp_tot / fmaxf(op_tot, tiny);
    }
}

extern "C" void kernel_launch(void* const* d_in, const int* in_sizes, int n_in,
                              void* d_out, int out_size, void* d_ws, size_t ws_size,
                              hipStream_t stream) {
    const float* rays_o      = (const float*)d_in[0];
    const float* rays_d      = (const float*)d_in[1];
    const float* W1          = (const float*)d_in[2];
    const float* b1          = (const float*)d_in[3];
    const float* W2          = (const float*)d_in[4];
    const float* b2          = (const float*)d_in[5];
    const float* t_starts    = (const float*)d_in[6];
    const int*   ray_indices = (const int*)d_in[8];

    const int n_rays    = in_sizes[0] / 3;
    const int n_samples = in_sizes[6];

    float*  out       = (float*)d_out;
    int*    first_idx = (int*)d_ws;                              // n_rays ints
    float2* smp       = (float2*)((char*)d_ws + SVAL_OFFSET);    // n_samples float2

    {
        const int waves  = (n_samples + WAVE_SAMPLES - 1) / WAVE_SAMPLES;
        const int blocks = (waves + 3) / 4;                      // 4 waves/block
        mlp_density_kernel<<<blocks, 256, 0, stream>>>(
            rays_o, rays_d, W1, b1, W2, b2, t_starts, ray_indices,
            smp, first_idx, n_samples, n_rays);
    }
    {
        const int blocks = (n_rays * 64 + 255) / 256;            // 1 wave/ray
        render_scan_kernel<<<blocks, 256, 0, stream>>>(
            smp, first_idx, out, n_rays, n_samples);
    }
}

// Round 14
// 110.906 us; speedup vs baseline: 1.0422x; 1.0345x over previous
//
#include <hip/hip_runtime.h>
#include <math.h>

#define HIDDEN 64
#define WAVE_SAMPLES 512          // samples per wave in the dense MLP kernel
#define SVAL_OFFSET 262144        // byte offset of packed {sval,tm} f16x2[] in d_ws

typedef _Float16 half8   __attribute__((ext_vector_type(8)));
typedef _Float16 half2_t __attribute__((ext_vector_type(2)));
typedef float    f32x16  __attribute__((ext_vector_type(16)));
typedef int      int4_t  __attribute__((ext_vector_type(4)));

// DPP add: v + dpp_perm(v), old=0, bound_ctrl=1.
template <int CTRL, int RMASK>
__device__ __forceinline__ float dpp_add(float v) {
    int t = __builtin_amdgcn_update_dpp(0, __builtin_bit_cast(int, v),
                                        CTRL, RMASK, 0xF, true);
    return v + __builtin_bit_cast(float, t);
}

__device__ __forceinline__ float bcast_lane(float v, int lane) {
    return __builtin_bit_cast(float,
        __builtin_amdgcn_readlane(__builtin_bit_cast(int, v), lane));
}

__device__ __forceinline__ half2_t pack2(float a, float b) {
    return __builtin_bit_cast(half2_t, __builtin_amdgcn_cvt_pkrtz(a, b));
}

__device__ __forceinline__ half2_t pk_relu(half2_t h) {
    half2_t r;
    asm("v_pk_max_f16 %0, %1, 0" : "=v"(r) : "v"(h));
    return r;
}

// full wave64 inclusive scan (6 DPP adds)
__device__ __forceinline__ float scan64(float v) {
    v = dpp_add<0x111, 0xF>(v);
    v = dpp_add<0x112, 0xF>(v);
    v = dpp_add<0x114, 0xF>(v);
    v = dpp_add<0x118, 0xF>(v);
    v = dpp_add<0x142, 0xA>(v);   // row_bcast:15 -> rows 1,3
    v = dpp_add<0x143, 0xC>(v);   // row_bcast:31 -> rows 2,3
    return v;
}

// layer1 (MFMA) + layer2 (pack/pk_relu/dot2) + cross-half combine -> z
__device__ __forceinline__ float mlp_z(half8 a0, half8 a1,
                                       const half2_t* w2a, const half2_t* w2b,
                                       half8 bf, int xaddr, float bias2) {
    const f32x16 zc = {};
    const f32x16 d0 = __builtin_amdgcn_mfma_f32_32x32x16_f16(a0, bf, zc, 0, 0, 0);
    const f32x16 d1 = __builtin_amdgcn_mfma_f32_32x32x16_f16(a1, bf, zc, 0, 0, 0);
    float c0 = 0.0f, c1 = 0.0f, c2 = 0.0f, c3 = 0.0f;
    #pragma unroll
    for (int r8 = 0; r8 < 8; r8 += 4) {
        c0 = __builtin_amdgcn_fdot2(pk_relu(pack2(d0[2*r8+0], d0[2*r8+1])), w2a[r8+0], c0, false);
        c1 = __builtin_amdgcn_fdot2(pk_relu(pack2(d0[2*r8+2], d0[2*r8+3])), w2a[r8+1], c1, false);
        c2 = __builtin_amdgcn_fdot2(pk_relu(pack2(d0[2*r8+4], d0[2*r8+5])), w2a[r8+2], c2, false);
        c3 = __builtin_amdgcn_fdot2(pk_relu(pack2(d0[2*r8+6], d0[2*r8+7])), w2a[r8+3], c3, false);
    }
    #pragma unroll
    for (int r8 = 0; r8 < 8; r8 += 4) {
        c0 = __builtin_amdgcn_fdot2(pk_relu(pack2(d1[2*r8+0], d1[2*r8+1])), w2b[r8+0], c0, false);
        c1 = __builtin_amdgcn_fdot2(pk_relu(pack2(d1[2*r8+2], d1[2*r8+3])), w2b[r8+1], c1, false);
        c2 = __builtin_amdgcn_fdot2(pk_relu(pack2(d1[2*r8+4], d1[2*r8+5])), w2b[r8+2], c2, false);
        c3 = __builtin_amdgcn_fdot2(pk_relu(pack2(d1[2*r8+6], d1[2*r8+7])), w2b[r8+3], c3, false);
    }
    const float acc = (c0 + c1) + (c2 + c3);
    const int oth = __builtin_amdgcn_ds_bpermute(xaddr, __builtin_bit_cast(int, acc));
    return acc + __builtin_bit_cast(float, oth) + bias2;
}

// Kernel 1 (dense, sample-parallel): packed {sval,tm} f16x2 per sample -> ws,
// fused first_idx scatter. No serial dependencies between iterations.
// launch_bounds (256,4): R11's best-measured register regime.
__global__ __launch_bounds__(256, 4) void mlp_density_kernel(
    const float* __restrict__ rays_o, const float* __restrict__ rays_d,
    const float* __restrict__ W1, const float* __restrict__ b1,
    const float* __restrict__ W2, const float* __restrict__ b2,
    const float* __restrict__ t_starts, const int* __restrict__ ray_indices,
    int* __restrict__ smp_out, int* __restrict__ first_idx,
    int n_samples, int n_rays)
{
    const int tid  = threadIdx.x;
    const int lane = tid & 63;
    const int wave = (blockIdx.x * blockDim.x + tid) >> 6;
    const int n = lane & 31;
    const int q = lane >> 5;

    const int base0 = wave * WAVE_SAMPLES;
    if (base0 >= n_samples) return;
    const int lim = (base0 + WAVE_SAMPLES < n_samples) ? (base0 + WAVE_SAMPLES) : n_samples;

    // ---- preamble: A fragments + W2 f16 pairs (in-register, proven) ----
    half8 a0 = {}, a1 = {};
    if (q == 0) {
        const int m = n;
        a0[0] = (_Float16)W1[0 * HIDDEN + m];
        a0[1] = (_Float16)W1[1 * HIDDEN + m];
        a0[2] = (_Float16)W1[2 * HIDDEN + m];
        a0[3] = (_Float16)b1[m];
        a1[0] = (_Float16)W1[0 * HIDDEN + 32 + m];
        a1[1] = (_Float16)W1[1 * HIDDEN + 32 + m];
        a1[2] = (_Float16)W1[2 * HIDDEN + 32 + m];
        a1[3] = (_Float16)b1[32 + m];
    }
    half2_t w2a[8], w2b[8];
    #pragma unroll
    for (int r8 = 0; r8 < 8; ++r8) {
        const int row = 2 * (r8 & 1) + 8 * (r8 >> 1) + 4 * q;
        half2_t pa, pb;
        pa[0] = (_Float16)W2[row];      pa[1] = (_Float16)W2[row + 1];
        pb[0] = (_Float16)W2[row + 32]; pb[1] = (_Float16)W2[row + 33];
        w2a[r8] = pa; w2b[r8] = pb;
    }
    const float bias2 = b2[0];
    const int xaddr = (lane ^ 32) << 2;
    const int bmask = (q == 0) ? ~0 : 0;

    for (int base = base0; base < lim; base += 64) {
        // ---- fused first_idx scatter: lane l covers sample base+l ----
        const int iS = base + lane;
        if (iS < n_samples) {
            const int cur  = ray_indices[iS];
            const int prev = (iS == 0) ? -1 : ray_indices[iS - 1];
            for (int r = prev + 1; r <= cur; ++r) first_idx[r] = iS;
            if (iS == n_samples - 1) {
                for (int r = cur + 1; r < n_rays; ++r) first_idx[r] = n_samples;
            }
        }

        // ---- density for samples base+n (half A) and base+32+n (half B) ----
        const int ia = base + n;
        const int ib = ia + 32;
        const bool va = (ia < n_samples);
        const bool vb = (ib < n_samples);
        const int ca = va ? ia : (n_samples - 1);
        const int cb = vb ? ib : (n_samples - 1);

        const float tm_a = t_starts[ca] + 0.0025f;   // te = ts + 0.005
        const float tm_b = t_starts[cb] + 0.0025f;
        const int   ria  = ray_indices[ca];
        const int   rib  = ray_indices[cb];

        const float pxa = fmaf(rays_d[3 * ria + 0], tm_a, rays_o[3 * ria + 0]);
        const float pya = fmaf(rays_d[3 * ria + 1], tm_a, rays_o[3 * ria + 1]);
        const float pza = fmaf(rays_d[3 * ria + 2], tm_a, rays_o[3 * ria + 2]);
        const float pxb = fmaf(rays_d[3 * rib + 0], tm_b, rays_o[3 * rib + 0]);
        const float pyb = fmaf(rays_d[3 * rib + 1], tm_b, rays_o[3 * rib + 1]);
        const float pzb = fmaf(rays_d[3 * rib + 2], tm_b, rays_o[3 * rib + 2]);

        const int a01 = __builtin_bit_cast(int, __builtin_amdgcn_cvt_pkrtz(pxa, pya)) & bmask;
        const int a23 = __builtin_bit_cast(int, __builtin_amdgcn_cvt_pkrtz(pza, 1.0f)) & bmask;
        const int b01 = __builtin_bit_cast(int, __builtin_amdgcn_cvt_pkrtz(pxb, pyb)) & bmask;
        const int b23 = __builtin_bit_cast(int, __builtin_amdgcn_cvt_pkrtz(pzb, 1.0f)) & bmask;
        const int4_t bia = {a01, a23, 0, 0};
        const int4_t bib = {b01, b23, 0, 0};

        const float z_a = mlp_z(a0, a1, w2a, w2b, __builtin_bit_cast(half8, bia), xaddr, bias2);
        const float z_b = mlp_z(a0, a1, w2a, w2b, __builtin_bit_cast(half8, bib), xaddr, bias2);

        const float sg_a = fmaxf(z_a, 0.0f) + __logf(1.0f + __expf(-fabsf(z_a)));
        const float sg_b = fmaxf(z_b, 0.0f) + __logf(1.0f + __expf(-fabsf(z_b)));

        if (q == 0) {
            if (va) smp_out[ia] = __builtin_bit_cast(int, pack2(sg_a * 0.005f, tm_a));
            if (vb) smp_out[ib] = __builtin_bit_cast(int, pack2(sg_b * 0.005f, tm_b));
        }
    }
}

// Kernel 2 (light): one wave64 per ray, lane = sample. ONE dword load per
// sample (packed f16 {sval,tm}); wave64 DPP scan -> weights -> opacity/depth.
__global__ __launch_bounds__(256, 8) void render_scan_kernel(
    const int* __restrict__ smp, const int* __restrict__ first_idx,
    float* __restrict__ out, int n_rays, int n_samples)
{
    const int tid  = threadIdx.x;
    const int lane = tid & 63;
    const int ray  = (blockIdx.x * blockDim.x + tid) >> 6;
    if (ray >= n_rays) return;

    const int seg_start = first_idx[ray];
    const int seg_end   = (ray + 1 < n_rays) ? first_idx[ray + 1] : n_samples;
    if (seg_start >= seg_end) {
        if (lane == 0) { out[2 * ray] = 0.0f; out[2 * ray + 1] = 0.0f; }
        return;
    }

    float carry = 0.0f, op_acc = 0.0f, depth_acc = 0.0f;
    const int last = seg_end - 1;

    for (int base = seg_start; base < seg_end; base += 64) {
        const int  i     = base + lane;
        const bool valid = (i < seg_end);
        const int  ic    = valid ? i : last;

        const half2_t v  = __builtin_bit_cast(half2_t, smp[ic]);
        const float   sv = valid ? (float)v[0] : 0.0f;
        const float   tm = (float)v[1];

        const float scan = scan64(sv);
        const float incl = carry + scan;
        const float w    = __expf(sv - incl) - __expf(-incl);   // 0 when sv==0

        op_acc    += w;
        depth_acc  = fmaf(w, tm, depth_acc);
        carry     += bcast_lane(scan, 63);
    }

    const float op_tot = bcast_lane(scan64(op_acc), 63);
    const float dp_tot = bcast_lane(scan64(depth_acc), 63);

    if (lane == 0) {
        const float tiny = 1.17549435e-38f;
        out[2 * ray + 0] = op_tot;
        out[2 * ray + 1] = dp_tot / fmaxf(op_tot, tiny);
    }
}

extern "C" void kernel_launch(void* const* d_in, const int* in_sizes, int n_in,
                              void* d_out, int out_size, void* d_ws, size_t ws_size,
                              hipStream_t stream) {
    const float* rays_o      = (const float*)d_in[0];
    const float* rays_d      = (const float*)d_in[1];
    const float* W1          = (const float*)d_in[2];
    const float* b1          = (const float*)d_in[3];
    const float* W2          = (const float*)d_in[4];
    const float* b2          = (const float*)d_in[5];
    const float* t_starts    = (const float*)d_in[6];
    const int*   ray_indices = (const int*)d_in[8];

    const int n_rays    = in_sizes[0] / 3;
    const int n_samples = in_sizes[6];

    float* out       = (float*)d_out;
    int*   first_idx = (int*)d_ws;                            // n_rays ints
    int*   smp       = (int*)((char*)d_ws + SVAL_OFFSET);     // n_samples words

    {
        const int waves  = (n_samples + WAVE_SAMPLES - 1) / WAVE_SAMPLES;
        const int blocks = (waves + 3) / 4;                   // 4 waves/block
        mlp_density_kernel<<<blocks, 256, 0, stream>>>(
            rays_o, rays_d, W1, b1, W2, b2, t_starts, ray_indices,
            smp, first_idx, n_samples, n_rays);
    }
    {
        const int blocks = (n_rays * 64 + 255) / 256;         // 1 wave/ray
        render_scan_kernel<<<blocks, 256, 0, stream>>>(
            smp, first_idx, out, n_rays, n_samples);
    }
}